// Round 13
// baseline (288.655 us; speedup 1.0000x reference)
//
#include <hip/hip_runtime.h>
#include <cstdint>
#include <cstddef>

// Problem constants
#define NB 2
#define NF 8
#define NS 4
#define NK 90      // real K (dirs per shell)
#define NP 642     // grid vertices
#define NXYZ 1728  // 12*12*12
#define MT 64      // p-tile
#define PTILES 11  // ceil(642/64)
#define NG 108     // xyz 16-groups (1728/16)
#define NPAIR 27   // n32-pairs (54/2)
#define GEMM_TASKS (64 * NPAIR * PTILES)  // 19008 wave tasks
#define GEMM_BLOCKS (GEMM_TASKS / 4)      // 4752 = 8 * 594 (exact -> bijective)
#define NXCD 8
#define CPX (GEMM_BLOCKS / NXCD)          // 594

typedef __attribute__((ext_vector_type(8))) __bf16 bf16x8;
typedef __attribute__((ext_vector_type(4))) float f32x4;
typedef __attribute__((ext_vector_type(4))) uint32_t u32x4;

// RNE pack of two f32 -> u32 holding 2 bf16 (validated R1-R12)
__device__ __forceinline__ uint32_t pack2bf(float a, float b) {
    uint32_t ua = __builtin_bit_cast(uint32_t, a);
    uint32_t ub = __builtin_bit_cast(uint32_t, b);
    ua += 0x7FFFu + ((ua >> 16) & 1u);
    ub += 0x7FFFu + ((ub >> 16) & 1u);
    return (ua >> 16) | (ub & 0xFFFF0000u);
}

// ============ Single fused kernel: R12's barrier-free 2-half GEMM, but
// operands loaded DIRECTLY from x/W with in-register bf16 packing — no prep
// dispatch, no ws. Rationale: gemm is ~80% memory-idle at issue level, so
// the extra strided loads + pack VALU hide under the write drain, while the
// ~11 µs serial prep kernel (and its 44 MB of ws round-trip) disappears.
// Locality: the 4 waves of a block = 4 consecutive pt of the SAME (e,pr)
// -> identical B-frag addresses (L1-served after wave 0); consecutive
// blocks share e (XCD-L2-resident x slice via T1 swizzle).
__global__ __launch_bounds__(256, 3) void gemm_direct(
    const float* __restrict__ x, const float* __restrict__ Wm,
    float* __restrict__ y)
{
    const int tid  = (int)threadIdx.x;
    const int lane = tid & 63;
    const int lr = lane & 15, lg = lane >> 4;

    const int i = (int)blockIdx.x;
    const int orig = (i % NXCD) * CPX + i / NXCD;   // bijective T1 swizzle
    int t = orig * 4 + (tid >> 6);
    const int pt = t % PTILES; t /= PTILES;   // pt fastest within block
    const int pr = t % NPAIR;  t /= NPAIR;    // n32-pair: n32 = 2*pr, 2*pr+1
    const int e  = t;                          // 0..63 = (b*8+f)*4 + s
    const int s = e & 3, bf = e >> 2;

    // ---- B-frags: x[e, k, g*16+lr], g = pr*4+gi. Per (gi,kk): 8 strided
    // dwords (lanes 0-15 = 64B contiguous), pack to bf16x8. k>=90 -> 0.
    const float* xe = x + (size_t)e * (NK * NXYZ);
    bf16x8 bfr[4][3];
    #pragma unroll
    for (int gi = 0; gi < 4; ++gi) {
        const float* src = xe + (pr * 4 + gi) * 16 + lr;
        #pragma unroll
        for (int kk = 0; kk < 3; ++kk) {
            float v[8];
            #pragma unroll
            for (int j = 0; j < 8; ++j) {
                const int k = kk * 32 + lg * 8 + j;
                v[j] = (k < NK) ? src[(size_t)k * NXYZ] : 0.f;
            }
            u32x4 u;
            u.x = pack2bf(v[0], v[1]);
            u.y = pack2bf(v[2], v[3]);
            u.z = pack2bf(v[4], v[5]);
            u.w = pack2bf(v[6], v[7]);
            bfr[gi][kk] = __builtin_bit_cast(bf16x8, u);
        }
    }

    // ---- A-frags: W[s, k, pt*64+ni*16+lr]. W is tiny (1.15 MB f32) -> L2.
    const float* we = Wm + (size_t)s * (NK * NP);
    bf16x8 afr[4][3];
    #pragma unroll
    for (int ni = 0; ni < 4; ++ni) {
        const int p = pt * MT + ni * 16 + lr;
        const bool pv = (p < NP);
        const float* src = we + p;
        #pragma unroll
        for (int kk = 0; kk < 3; ++kk) {
            float v[8];
            #pragma unroll
            for (int j = 0; j < 8; ++j) {
                const int k = kk * 32 + lg * 8 + j;
                v[j] = (pv && k < NK) ? src[(size_t)k * NP] : 0.f;
            }
            u32x4 u;
            u.x = pack2bf(v[0], v[1]);
            u.y = pack2bf(v[2], v[3]);
            u.z = pack2bf(v[4], v[5]);
            u.w = pack2bf(v[6], v[7]);
            afr[ni][kk] = __builtin_bit_cast(bf16x8, u);
        }
    }

    // ---- Compute + store: identical to R12's validated gemm_frag2.
    const int b = bf >> 3, f = bf & 7;
    const size_t chan = (size_t)b * (NS * NF) + (size_t)s * NF + f;
    float* ybase = y + chan * ((size_t)NP * NXYZ) + pr * 64 + lg * 4;

    #pragma unroll
    for (int h = 0; h < 2; ++h) {       // two n32 halves, acc/regs reused
        f32x4 acc[2][4];
        #pragma unroll
        for (int mi = 0; mi < 2; ++mi)
            #pragma unroll
            for (int ni = 0; ni < 4; ++ni)
                acc[mi][ni] = (f32x4){0.f, 0.f, 0.f, 0.f};

        #pragma unroll
        for (int kk = 0; kk < 3; ++kk)
            #pragma unroll
            for (int mi = 0; mi < 2; ++mi)
                #pragma unroll
                for (int ni = 0; ni < 4; ++ni)
                    acc[mi][ni] = __builtin_amdgcn_mfma_f32_16x16x32_bf16(
                        bfr[h * 2 + mi][kk], afr[ni][kk], acc[mi][ni], 0, 0, 0);

        float* yh = ybase + h * 32;
        #pragma unroll
        for (int ni = 0; ni < 4; ++ni) {
            const int p = pt * MT + ni * 16 + lr;
            if (p < NP) {
                float* dst = yh + (size_t)p * NXYZ;
                *(f32x4*)dst = acc[0][ni];
                *(f32x4*)(dst + 16) = acc[1][ni];
            }
        }
    }
}

extern "C" void kernel_launch(void* const* d_in, const int* in_sizes, int n_in,
                              void* d_out, int out_size, void* d_ws, size_t ws_size,
                              hipStream_t stream) {
    (void)in_sizes; (void)n_in; (void)out_size; (void)d_ws; (void)ws_size;
    const float* x  = (const float*)d_in[0];
    const float* Wm = (const float*)d_in[1];
    // d_in[2] (shell_inverse) is sorted contiguous by construction -> static layout.
    float* y = (float*)d_out;
    gemm_direct<<<GEMM_BLOCKS, 256, 0, stream>>>(x, Wm, y);
}

// Round 14
// 75.423 us; speedup vs baseline: 3.8272x; 3.8272x over previous
//
#include <hip/hip_runtime.h>
#include <cstdint>
#include <cstddef>

// Problem constants
#define NB 2
#define NF 8
#define NS 4
#define NK 90      // real K (dirs per shell)
#define NP 642     // grid vertices
#define NXYZ 1728  // 12*12*12
#define MT 64      // p-tile
#define PTILES 11  // ceil(642/64)
#define NG 108     // xyz 16-groups (1728/16)
#define XT_TASKS (64 * NG * 3)          // 20736 x-fragment blocks (1 KB each)
#define WT_TASKS (NS * PTILES * 4 * 3)  // 528 W-fragment blocks
#define NPAIR 27                        // n32-pairs (54/2)
#define NTRI 9                          // pr-triples (27/3)
#define GEMM_BLOCKS (64 * PTILES * NTRI)  // 6336 = 8 * 792 (exact -> bijective)
#define NXCD 8
#define CPX (GEMM_BLOCKS / NXCD)          // 792

typedef __attribute__((ext_vector_type(8))) __bf16 bf16x8;
typedef __attribute__((ext_vector_type(4))) float f32x4;
typedef __attribute__((ext_vector_type(4))) uint32_t u32x4;

// RNE pack of two f32 -> u32 holding 2 bf16 (validated R1-R13)
__device__ __forceinline__ uint32_t pack2bf(float a, float b) {
    uint32_t ua = __builtin_bit_cast(uint32_t, a);
    uint32_t ub = __builtin_bit_cast(uint32_t, b);
    ua += 0x7FFFu + ((ua >> 16) & 1u);
    ub += 0x7FFFu + ((ub >> 16) & 1u);
    return (ua >> 16) | (ub & 0xFFFF0000u);
}

// ============ Kernel 1: pack x and W into MFMA-fragment-order bf16 blocks.
// (R5 structure — fastest prep measured; R13 proved the split is essential:
// fused direct loads were 3.5x slower, VMEM-issue-bound.)
__global__ __launch_bounds__(256) void prep_frag(
    const float* __restrict__ x, const float* __restrict__ Wm,
    uint32_t* __restrict__ ws)
{
    const int tid  = (int)threadIdx.x;
    const int lane = tid & 63;
    const int lr = lane & 15, lg = lane >> 4;
    const int task = (int)blockIdx.x * 4 + (tid >> 6);

    float v[8];
    if (task < XT_TASKS) {
        int t = task;
        const int kk = t % 3;   t /= 3;
        const int g  = t % NG;  t /= NG;
        const int e  = t;                  // 0..63
        const int s = e & 3, bf = e >> 2;
        const float* src = x + (size_t)bf * (NS * NK * NXYZ)
                             + (size_t)s * (NK * NXYZ) + g * 16 + lr;
        #pragma unroll
        for (int j = 0; j < 8; ++j) {
            const int k = kk * 32 + lg * 8 + j;
            v[j] = (k < NK) ? src[(size_t)k * NXYZ] : 0.f;
        }
    } else {
        int t = task - XT_TASKS;
        const int kk = t % 3;      t /= 3;
        const int ni = t % 4;      t /= 4;
        const int pt = t % PTILES; t /= PTILES;
        const int s  = t;                  // 0..3
        const int p = pt * MT + ni * 16 + lr;
        const float* src = Wm + (size_t)s * (NK * NP) + p;
        #pragma unroll
        for (int j = 0; j < 8; ++j) {
            const int k = kk * 32 + lg * 8 + j;
            v[j] = (k < NK && p < NP) ? src[(size_t)k * NP] : 0.f;
        }
    }
    u32x4 u;
    u.x = pack2bf(v[0], v[1]);
    u.y = pack2bf(v[2], v[3]);
    u.z = pack2bf(v[4], v[5]);
    u.w = pack2bf(v[6], v[7]);
    *(u32x4*)((char*)ws + (size_t)task * 1024 + lane * 16) = u;
}

// ============ Kernel 2: R12's pair-wave GEMM with WRITE-LOCALITY regrouping.
// Wave work is byte-identical to R12 (24 frag loads, 48 MFMA, 16 stores,
// 2-half acc reuse). Only the block/wave->task mapping changes:
//   block = (e, pt, tri), 3 waves = 3 consecutive pr of the SAME pt
//   -> block writes 64 rows x 768 B contiguous;
//   tri fastest -> 9 consecutive blocks complete FULL 6.9 KB rows;
//   XCD chunk (792 blocks) = 8 e values -> x_t slice 2.6 MB fits XCD L2,
//   and each XCD's write stream is long dense row-complete regions.
// A-frags now identical across the 3 waves AND the 9 tri-sibling blocks.
__global__ __launch_bounds__(192, 3) void gemm_frag3(
    const uint32_t* __restrict__ ws, float* __restrict__ y)
{
    const int tid  = (int)threadIdx.x;
    const int lane = tid & 63;
    const int lr = lane & 15, lg = lane >> 4;
    const int w    = tid >> 6;                 // 0..2

    const int i = (int)blockIdx.x;
    const int orig = (i % NXCD) * CPX + i / NXCD;   // bijective: 6336 = 8*792
    const int tri = orig % NTRI;
    const int pt  = (orig / NTRI) % PTILES;
    const int e   = orig / (NTRI * PTILES);         // 0..63
    const int pr  = tri * 3 + w;                    // 0..26
    const int s = e & 3, bf = e >> 2;

    const char* base  = (const char*)ws + (size_t)lane * 16;
    // B-frags: 4 16-groups (g = pr*4 .. pr*4+3) x 3 kk
    const char* xbase = base + (size_t)((e * NG + pr * 4) * 3) * 1024;
    const char* abase = base + (size_t)(XT_TASKS + ((s * PTILES + pt) * 4) * 3) * 1024;

    bf16x8 bfr[4][3], afr[4][3];
    #pragma unroll
    for (int gi = 0; gi < 4; ++gi)
        #pragma unroll
        for (int kk = 0; kk < 3; ++kk)
            bfr[gi][kk] = *(const bf16x8*)(xbase + (gi * 3 + kk) * 1024);
    #pragma unroll
    for (int ni = 0; ni < 4; ++ni)
        #pragma unroll
        for (int kk = 0; kk < 3; ++kk)
            afr[ni][kk] = *(const bf16x8*)(abase + (ni * 3 + kk) * 1024);

    const int b = bf >> 3, f = bf & 7;
    const size_t chan = (size_t)b * (NS * NF) + (size_t)s * NF + f;
    float* ybase = y + chan * ((size_t)NP * NXYZ) + pr * 64 + lg * 4;

    #pragma unroll
    for (int h = 0; h < 2; ++h) {       // two n32 halves, acc/regs reused
        f32x4 acc[2][4];
        #pragma unroll
        for (int mi = 0; mi < 2; ++mi)
            #pragma unroll
            for (int ni = 0; ni < 4; ++ni)
                acc[mi][ni] = (f32x4){0.f, 0.f, 0.f, 0.f};

        #pragma unroll
        for (int kk = 0; kk < 3; ++kk)
            #pragma unroll
            for (int mi = 0; mi < 2; ++mi)
                #pragma unroll
                for (int ni = 0; ni < 4; ++ni)
                    acc[mi][ni] = __builtin_amdgcn_mfma_f32_16x16x32_bf16(
                        bfr[h * 2 + mi][kk], afr[ni][kk], acc[mi][ni], 0, 0, 0);

        float* yh = ybase + h * 32;
        #pragma unroll
        for (int ni = 0; ni < 4; ++ni) {
            const int p = pt * MT + ni * 16 + lr;
            if (p < NP) {
                float* dst = yh + (size_t)p * NXYZ;
                *(f32x4*)dst = acc[0][ni];
                *(f32x4*)(dst + 16) = acc[1][ni];
            }
        }
    }
}

// ============ Fallback (round-3 structure) if ws too small ================
#define NT 96
#define NTILES 18
#define KP 96
#define ROWB (KP * 2)

__global__ __launch_bounds__(192, 4) void interp_fallback(
    const float* __restrict__ x, const float* __restrict__ Wm,
    float* __restrict__ y)
{
    __shared__ __align__(16) char As[MT * ROWB];
    __shared__ __align__(16) char Bs[NT * ROWB];

    int blk = (int)blockIdx.x;
    const int nt = blk % NTILES; blk /= NTILES;
    const int f  = blk % NF;     blk /= NF;
    const int s  = blk % NS;     blk /= NS;
    const int b  = blk;
    const int tid = (int)threadIdx.x;
    const int n0 = nt * NT;

    {
        const int c  = tid % NT;
        const int kh = tid / NT;
        const float* xp = x + (((size_t)b * NF + f) * (NS * NK) + (size_t)s * NK) * NXYZ
                            + n0 + c;
        const int cs = (c & 7) << 4;
        #pragma unroll
        for (int kk = 0; kk < 48; kk += 8) {
            const int kb = kh * 48 + kk;
            float v[8];
            #pragma unroll
            for (int j = 0; j < 8; ++j) {
                const int k = kb + j;
                v[j] = (k < NK) ? xp[(size_t)k * NXYZ] : 0.f;
            }
            u32x4 u;
            u.x = pack2bf(v[0], v[1]); u.y = pack2bf(v[2], v[3]);
            u.z = pack2bf(v[4], v[5]); u.w = pack2bf(v[6], v[7]);
            *(u32x4*)(Bs + ((c * ROWB + kb * 2) ^ cs)) = u;
        }
    }

    const int lane = tid & 63;
    const int w  = tid / 64;
    const int lr = lane & 15;
    const int lg = lane >> 4;
    const int ls = (lr & 7) << 4;
    const size_t chan = (size_t)b * (NS * NF) + (size_t)s * NF + f;
    float* ybase = y + chan * ((size_t)NP * NXYZ);
    const int xyzbase = n0 + w * 32 + lg * 4;
    const int ar = tid & 63;
    const int akc = tid >> 6;
    const int ars = (ar & 7) << 4;

    for (int pt = 0; pt < PTILES; ++pt) {
        const int p0 = pt * MT;
        __syncthreads();
        {
            const int p = p0 + ar;
            const bool pv = (p < NP);
            const float* wp = Wm + (size_t)s * NK * NP + p;
            #pragma unroll
            for (int kk = 0; kk < 32; kk += 8) {
                const int kb = akc * 32 + kk;
                float v[8];
                #pragma unroll
                for (int j = 0; j < 8; ++j) {
                    const int k = kb + j;
                    v[j] = (pv && (k < NK)) ? wp[(size_t)k * NP] : 0.f;
                }
                u32x4 u;
                u.x = pack2bf(v[0], v[1]); u.y = pack2bf(v[2], v[3]);
                u.z = pack2bf(v[4], v[5]); u.w = pack2bf(v[6], v[7]);
                *(u32x4*)(As + ((ar * ROWB + kb * 2) ^ ars)) = u;
            }
        }
        __syncthreads();

        f32x4 acc[2][4];
        #pragma unroll
        for (int mi = 0; mi < 2; ++mi)
            #pragma unroll
            for (int ni = 0; ni < 4; ++ni)
                acc[mi][ni] = (f32x4){0.f, 0.f, 0.f, 0.f};

        #pragma unroll
        for (int kk = 0; kk < 3; ++kk) {
            const int kbyte = kk * 64 + lg * 16;
            bf16x8 bxyz[2], ap[4];
            #pragma unroll
            for (int mi = 0; mi < 2; ++mi) {
                const int row = w * 32 + mi * 16 + lr;
                bxyz[mi] = *(const bf16x8*)(Bs + ((row * ROWB + kbyte) ^ ls));
            }
            #pragma unroll
            for (int ni = 0; ni < 4; ++ni) {
                const int row = ni * 16 + lr;
                ap[ni] = *(const bf16x8*)(As + ((row * ROWB + kbyte) ^ ls));
            }
            #pragma unroll
            for (int mi = 0; mi < 2; ++mi)
                #pragma unroll
                for (int ni = 0; ni < 4; ++ni)
                    acc[mi][ni] = __builtin_amdgcn_mfma_f32_16x16x32_bf16(
                        bxyz[mi], ap[ni], acc[mi][ni], 0, 0, 0);
        }

        #pragma unroll
        for (int ni = 0; ni < 4; ++ni) {
            const int p = p0 + ni * 16 + lr;
            if (p < NP) {
                float* dst = ybase + (size_t)p * NXYZ + xyzbase;
                *(f32x4*)dst = acc[0][ni];
                *(f32x4*)(dst + 16) = acc[1][ni];
            }
        }
    }
}

extern "C" void kernel_launch(void* const* d_in, const int* in_sizes, int n_in,
                              void* d_out, int out_size, void* d_ws, size_t ws_size,
                              hipStream_t stream) {
    (void)in_sizes; (void)n_in; (void)out_size;
    const float* x  = (const float*)d_in[0];
    const float* Wm = (const float*)d_in[1];
    float* y = (float*)d_out;

    const size_t ws_need = (size_t)(XT_TASKS + WT_TASKS) * 1024;  // ~21.8 MB
    if (ws_size >= ws_need) {
        prep_frag<<<(XT_TASKS + WT_TASKS) / 4, 256, 0, stream>>>(x, Wm, (uint32_t*)d_ws);
        gemm_frag3<<<GEMM_BLOCKS, 192, 0, stream>>>((const uint32_t*)d_ws, y);
    } else {
        interp_fallback<<<NB * NS * NF * NTILES, 192, 0, stream>>>(x, Wm, y);
    }
}

// Round 15
// 73.737 us; speedup vs baseline: 3.9147x; 1.0229x over previous
//
#include <hip/hip_runtime.h>
#include <cstdint>
#include <cstddef>

// Problem constants
#define NB 2
#define NF 8
#define NS 4
#define NK 90      // real K (dirs per shell)
#define NP 642     // grid vertices
#define NXYZ 1728  // 12*12*12
#define MT 64      // p-tile
#define PTILES 11  // ceil(642/64)
#define NG 108     // xyz 16-groups (1728/16)
#define XT_TASKS (64 * NG * 3)          // 20736 x-fragment blocks (1 KB each)
#define WT_TASKS (NS * PTILES * 4 * 3)  // 528 W-fragment blocks
#define NWG 18                          // wave-groups of 96 cols (1728/96)
#define GEMM_BLOCKS (64 * PTILES * 6)   // 4224 = 8 * 528 (exact -> bijective)
#define NXCD 8
#define CPX (GEMM_BLOCKS / NXCD)        // 528

typedef __attribute__((ext_vector_type(8))) __bf16 bf16x8;
typedef __attribute__((ext_vector_type(4))) float f32x4;
typedef __attribute__((ext_vector_type(4))) uint32_t u32x4;

// RNE pack of two f32 -> u32 holding 2 bf16 (validated R1-R14)
__device__ __forceinline__ uint32_t pack2bf(float a, float b) {
    uint32_t ua = __builtin_bit_cast(uint32_t, a);
    uint32_t ub = __builtin_bit_cast(uint32_t, b);
    ua += 0x7FFFu + ((ua >> 16) & 1u);
    ub += 0x7FFFu + ((ub >> 16) & 1u);
    return (ua >> 16) | (ub & 0xFFFF0000u);
}

// ============ Kernel 1: pack x and W into MFMA-fragment-order bf16 blocks.
// (R5 structure — fastest prep measured; R13 proved the split is essential.)
__global__ __launch_bounds__(256) void prep_frag(
    const float* __restrict__ x, const float* __restrict__ Wm,
    uint32_t* __restrict__ ws)
{
    const int tid  = (int)threadIdx.x;
    const int lane = tid & 63;
    const int lr = lane & 15, lg = lane >> 4;
    const int task = (int)blockIdx.x * 4 + (tid >> 6);

    float v[8];
    if (task < XT_TASKS) {
        int t = task;
        const int kk = t % 3;   t /= 3;
        const int g  = t % NG;  t /= NG;
        const int e  = t;                  // 0..63
        const int s = e & 3, bf = e >> 2;
        const float* src = x + (size_t)bf * (NS * NK * NXYZ)
                             + (size_t)s * (NK * NXYZ) + g * 16 + lr;
        #pragma unroll
        for (int j = 0; j < 8; ++j) {
            const int k = kk * 32 + lg * 8 + j;
            v[j] = (k < NK) ? src[(size_t)k * NXYZ] : 0.f;
        }
    } else {
        int t = task - XT_TASKS;
        const int kk = t % 3;      t /= 3;
        const int ni = t % 4;      t /= 4;
        const int pt = t % PTILES; t /= PTILES;
        const int s  = t;                  // 0..3
        const int p = pt * MT + ni * 16 + lr;
        const float* src = Wm + (size_t)s * (NK * NP) + p;
        #pragma unroll
        for (int j = 0; j < 8; ++j) {
            const int k = kk * 32 + lg * 8 + j;
            v[j] = (k < NK && p < NP) ? src[(size_t)k * NP] : 0.f;
        }
    }
    u32x4 u;
    u.x = pack2bf(v[0], v[1]);
    u.y = pack2bf(v[2], v[3]);
    u.z = pack2bf(v[4], v[5]);
    u.w = pack2bf(v[6], v[7]);
    *(u32x4*)((char*)ws + (size_t)task * 1024 + lane * 16) = u;
}

// ============ Kernel 2: TRIPLE-n32 GEMM. Wave = (e, pt, wave-group of 96
// cols): 12 A-frags loaded once, reused across 3 n32-halves; B-frags loaded
// per-half with explicit compile-time ping-pong (bA/bB) so half h+1's loads
// hide under half h's MFMA+stores. Per wave: 30 loads, 72 MFMA, 24 stores
// (R12 pair: 24/48/16). Waves 19008 -> 12672. ~148 VGPR -> 3 waves/SIMD.
// Block = (e, pt, sext), 3 waves; sext fastest -> 6 sibling blocks complete
// full 6.9 KB output rows (R14 write grouping). T1 bijective XCD swizzle.
__global__ __launch_bounds__(192, 3) void gemm_frag3n(
    const uint32_t* __restrict__ ws, float* __restrict__ y)
{
    const int tid  = (int)threadIdx.x;
    const int lane = tid & 63;
    const int lr = lane & 15, lg = lane >> 4;
    const int w    = tid >> 6;                 // 0..2

    const int i = (int)blockIdx.x;
    const int orig = (i % NXCD) * CPX + i / NXCD;   // bijective: 4224 = 8*528
    const int sext = orig % 6;
    const int pt   = (orig / 6) % PTILES;
    const int e    = orig / 66;                     // 0..63
    const int wg   = sext * 3 + w;                  // 0..17, 96 cols each
    const int s = e & 3, bf = e >> 2;

    const char* base  = (const char*)ws + (size_t)lane * 16;
    // B-frag (h, mi, kk): g = wg*6 + h*2 + mi
    const char* xbase = base + (size_t)((e * NG + wg * 6) * 3) * 1024;
    const char* abase = base + (size_t)(XT_TASKS + ((s * PTILES + pt) * 4) * 3) * 1024;

    // A-frags: loaded once, reused for all 3 halves.
    bf16x8 afr[4][3];
    #pragma unroll
    for (int ni = 0; ni < 4; ++ni)
        #pragma unroll
        for (int kk = 0; kk < 3; ++kk)
            afr[ni][kk] = *(const bf16x8*)(abase + (ni * 3 + kk) * 1024);

    const int b = bf >> 3, f = bf & 7;
    const size_t chan = (size_t)b * (NS * NF) + (size_t)s * NF + f;
    float* ybase = y + chan * ((size_t)NP * NXYZ) + wg * 96 + lg * 4;

    bf16x8 bA[6], bB[6];   // ping-pong: 6 frags = one half (2 g x 3 kk)

    // load half 0 into bA
    #pragma unroll
    for (int q = 0; q < 6; ++q)
        bA[q] = *(const bf16x8*)(xbase + q * 1024);

#define COMPUTE_STORE(BSET, H)                                              \
    {                                                                       \
        f32x4 acc[2][4];                                                    \
        _Pragma("unroll")                                                   \
        for (int kk = 0; kk < 3; ++kk)                                      \
            _Pragma("unroll")                                               \
            for (int mi = 0; mi < 2; ++mi)                                  \
                _Pragma("unroll")                                           \
                for (int ni = 0; ni < 4; ++ni)                              \
                    acc[mi][ni] = __builtin_amdgcn_mfma_f32_16x16x32_bf16(  \
                        BSET[mi * 3 + kk], afr[ni][kk],                     \
                        kk ? acc[mi][ni] : (f32x4){0.f, 0.f, 0.f, 0.f},     \
                        0, 0, 0);                                           \
        float* yh = ybase + (H) * 32;                                       \
        _Pragma("unroll")                                                   \
        for (int ni = 0; ni < 4; ++ni) {                                    \
            const int p = pt * MT + ni * 16 + lr;                           \
            if (p < NP) {                                                   \
                float* dst = yh + (size_t)p * NXYZ;                         \
                *(f32x4*)dst = acc[0][ni];                                  \
                *(f32x4*)(dst + 16) = acc[1][ni];                           \
            }                                                               \
        }                                                                   \
    }

    // h=0: prefetch half 1 into bB, compute/store from bA
    #pragma unroll
    for (int q = 0; q < 6; ++q)
        bB[q] = *(const bf16x8*)(xbase + (6 + q) * 1024);
    COMPUTE_STORE(bA, 0)

    // h=1: prefetch half 2 into bA, compute/store from bB
    #pragma unroll
    for (int q = 0; q < 6; ++q)
        bA[q] = *(const bf16x8*)(xbase + (12 + q) * 1024);
    COMPUTE_STORE(bB, 1)

    // h=2: compute/store from bA
    COMPUTE_STORE(bA, 2)
#undef COMPUTE_STORE
}

// ============ Fallback (round-3 structure) if ws too small ================
#define NT 96
#define NTILES 18
#define KP 96
#define ROWB (KP * 2)

__global__ __launch_bounds__(192, 4) void interp_fallback(
    const float* __restrict__ x, const float* __restrict__ Wm,
    float* __restrict__ y)
{
    __shared__ __align__(16) char As[MT * ROWB];
    __shared__ __align__(16) char Bs[NT * ROWB];

    int blk = (int)blockIdx.x;
    const int nt = blk % NTILES; blk /= NTILES;
    const int f  = blk % NF;     blk /= NF;
    const int s  = blk % NS;     blk /= NS;
    const int b  = blk;
    const int tid = (int)threadIdx.x;
    const int n0 = nt * NT;

    {
        const int c  = tid % NT;
        const int kh = tid / NT;
        const float* xp = x + (((size_t)b * NF + f) * (NS * NK) + (size_t)s * NK) * NXYZ
                            + n0 + c;
        const int cs = (c & 7) << 4;
        #pragma unroll
        for (int kk = 0; kk < 48; kk += 8) {
            const int kb = kh * 48 + kk;
            float v[8];
            #pragma unroll
            for (int j = 0; j < 8; ++j) {
                const int k = kb + j;
                v[j] = (k < NK) ? xp[(size_t)k * NXYZ] : 0.f;
            }
            u32x4 u;
            u.x = pack2bf(v[0], v[1]); u.y = pack2bf(v[2], v[3]);
            u.z = pack2bf(v[4], v[5]); u.w = pack2bf(v[6], v[7]);
            *(u32x4*)(Bs + ((c * ROWB + kb * 2) ^ cs)) = u;
        }
    }

    const int lane = tid & 63;
    const int w  = tid / 64;
    const int lr = lane & 15;
    const int lg = lane >> 4;
    const int ls = (lr & 7) << 4;
    const size_t chan = (size_t)b * (NS * NF) + (size_t)s * NF + f;
    float* ybase = y + chan * ((size_t)NP * NXYZ);
    const int xyzbase = n0 + w * 32 + lg * 4;
    const int ar = tid & 63;
    const int akc = tid >> 6;
    const int ars = (ar & 7) << 4;

    for (int pt = 0; pt < PTILES; ++pt) {
        const int p0 = pt * MT;
        __syncthreads();
        {
            const int p = p0 + ar;
            const bool pv = (p < NP);
            const float* wp = Wm + (size_t)s * NK * NP + p;
            #pragma unroll
            for (int kk = 0; kk < 32; kk += 8) {
                const int kb = akc * 32 + kk;
                float v[8];
                #pragma unroll
                for (int j = 0; j < 8; ++j) {
                    const int k = kb + j;
                    v[j] = (pv && (k < NK)) ? wp[(size_t)k * NP] : 0.f;
                }
                u32x4 u;
                u.x = pack2bf(v[0], v[1]); u.y = pack2bf(v[2], v[3]);
                u.z = pack2bf(v[4], v[5]); u.w = pack2bf(v[6], v[7]);
                *(u32x4*)(As + ((ar * ROWB + kb * 2) ^ ars)) = u;
            }
        }
        __syncthreads();

        f32x4 acc[2][4];
        #pragma unroll
        for (int mi = 0; mi < 2; ++mi)
            #pragma unroll
            for (int ni = 0; ni < 4; ++ni)
                acc[mi][ni] = (f32x4){0.f, 0.f, 0.f, 0.f};

        #pragma unroll
        for (int kk = 0; kk < 3; ++kk) {
            const int kbyte = kk * 64 + lg * 16;
            bf16x8 bxyz[2], ap[4];
            #pragma unroll
            for (int mi = 0; mi < 2; ++mi) {
                const int row = w * 32 + mi * 16 + lr;
                bxyz[mi] = *(const bf16x8*)(Bs + ((row * ROWB + kbyte) ^ ls));
            }
            #pragma unroll
            for (int ni = 0; ni < 4; ++ni) {
                const int row = ni * 16 + lr;
                ap[ni] = *(const bf16x8*)(As + ((row * ROWB + kbyte) ^ ls));
            }
            #pragma unroll
            for (int mi = 0; mi < 2; ++mi)
                #pragma unroll
                for (int ni = 0; ni < 4; ++ni)
                    acc[mi][ni] = __builtin_amdgcn_mfma_f32_16x16x32_bf16(
                        bxyz[mi], ap[ni], acc[mi][ni], 0, 0, 0);
        }

        #pragma unroll
        for (int ni = 0; ni < 4; ++ni) {
            const int p = p0 + ni * 16 + lr;
            if (p < NP) {
                float* dst = ybase + (size_t)p * NXYZ + xyzbase;
                *(f32x4*)dst = acc[0][ni];
                *(f32x4*)(dst + 16) = acc[1][ni];
            }
        }
    }
}

extern "C" void kernel_launch(void* const* d_in, const int* in_sizes, int n_in,
                              void* d_out, int out_size, void* d_ws, size_t ws_size,
                              hipStream_t stream) {
    (void)in_sizes; (void)n_in; (void)out_size;
    const float* x  = (const float*)d_in[0];
    const float* Wm = (const float*)d_in[1];
    float* y = (float*)d_out;

    const size_t ws_need = (size_t)(XT_TASKS + WT_TASKS) * 1024;  // ~21.8 MB
    if (ws_size >= ws_need) {
        prep_frag<<<(XT_TASKS + WT_TASKS) / 4, 256, 0, stream>>>(x, Wm, (uint32_t*)d_ws);
        gemm_frag3n<<<GEMM_BLOCKS, 192, 0, stream>>>((const uint32_t*)d_ws, y);
    } else {
        interp_fallback<<<NB * NS * NF * NTILES, 192, 0, stream>>>(x, Wm, y);
    }
}